// Round 8
// baseline (691.321 us; speedup 1.0000x reference)
//
#include <hip/hip_runtime.h>
#include <hip/hip_fp8.h>

#define HD 4096   // H*D
#define Dd 128
#define Hh 32
#define KVBLK 32

typedef float f32x4 __attribute__((ext_vector_type(4)));
typedef float f32x2 __attribute__((ext_vector_type(2)));
typedef short s16x8 __attribute__((ext_vector_type(8)));

#define EXP2F(x) __builtin_amdgcn_exp2f(x)

// ---------- fp8 e4m3fn helpers (OCP on gfx950) ----------
__device__ inline unsigned char f8_quant_byte(float x_over_scale) {
    float c = fminf(fmaxf(x_over_scale, -448.0f), 448.0f);
    __hip_fp8_e4m3 f8(c);
    return (unsigned char)f8.__x;
}
// HW packed cvt: 2 fp8 (from 16-bit half of src) -> 2 f32
__device__ inline f32x2 f8x2_to_f32(unsigned src, bool hi) {
    return hi ? __builtin_amdgcn_cvt_pk_f32_fp8((int)src, true)
              : __builtin_amdgcn_cvt_pk_f32_fp8((int)src, false);
}
// HW packed cvt: 2 f32 -> packed bf16x2 (lo -> bits[15:0])
__device__ inline unsigned pk_bf16(float lo, float hi) {
    unsigned r;
    asm("v_cvt_pk_bf16_f32 %0, %1, %2" : "=v"(r) : "v"(lo), "v"(hi));
    return r;
}
__device__ inline long pack8(const unsigned char* b) {
    unsigned lo = (unsigned)b[0] | ((unsigned)b[1] << 8) | ((unsigned)b[2] << 16) | ((unsigned)b[3] << 24);
    unsigned hi = (unsigned)b[4] | ((unsigned)b[5] << 8) | ((unsigned)b[6] << 16) | ((unsigned)b[7] << 24);
    return (long)(((unsigned long long)hi << 32) | lo);
}

// ---------- kernel 1: fused per-tensor absmax (blockIdx.y selects tensor) ----------
__global__ void absmax_all_kernel(const float* __restrict__ q, const float* __restrict__ k,
                                  const float* __restrict__ v, int n4, unsigned* __restrict__ out) {
    const float* x = (blockIdx.y == 0) ? q : (blockIdx.y == 1) ? k : v;
    int i = blockIdx.x * blockDim.x + threadIdx.x;
    int stride = gridDim.x * blockDim.x;
    const float4* x4 = (const float4*)x;
    float m = 0.0f;
    for (; i < n4; i += stride) {
        float4 w = x4[i];
        m = fmaxf(m, fmaxf(fmaxf(fabsf(w.x), fabsf(w.y)), fmaxf(fabsf(w.z), fabsf(w.w))));
    }
    #pragma unroll
    for (int s = 32; s >= 1; s >>= 1) m = fmaxf(m, __shfl_xor(m, s, 64));
    __shared__ float red[4];
    int wid = threadIdx.x >> 6;
    if ((threadIdx.x & 63) == 0) red[wid] = m;
    __syncthreads();
    if (threadIdx.x == 0) {
        float mm = fmaxf(fmaxf(red[0], red[1]), fmaxf(red[2], red[3]));
        atomicMax(out + blockIdx.y, __float_as_uint(mm));
    }
}

// ---------- kernel 2: quantize K row-major -> fp8 bytes ----------
__global__ void quant_kernel(const float* __restrict__ x, unsigned char* __restrict__ q,
                             int n4, const unsigned* __restrict__ amax_bits) {
    float scale = __uint_as_float(*amax_bits) / 448.0f;
    int i = blockIdx.x * blockDim.x + threadIdx.x;
    int stride = gridDim.x * blockDim.x;
    const float4* x4 = (const float4*)x;
    unsigned* q4 = (unsigned*)q;
    for (; i < n4; i += stride) {
        float4 v = x4[i];
        unsigned p = (unsigned)f8_quant_byte(v.x / scale)
                   | ((unsigned)f8_quant_byte(v.y / scale) << 8)
                   | ((unsigned)f8_quant_byte(v.z / scale) << 16)
                   | ((unsigned)f8_quant_byte(v.w / scale) << 24);
        q4[i] = p;
    }
}

// ---------- kernel 3: quantize V + transpose -> V8T[hd][t] fp8 bytes ----------
// tiles: 64 t-rows x 32 hd-cols through a padded LDS byte tile
__global__ __launch_bounds__(256)
void quant_vt_kernel(const float* __restrict__ v, unsigned char* __restrict__ vt,
                     int total, const unsigned* __restrict__ amax_bits) {
    __shared__ unsigned char Tl[32 * 68];   // [hd][t] padded: stride 68
    float scale = __uint_as_float(*amax_bits) / 448.0f;
    int t0 = blockIdx.x * 64, hd0 = blockIdx.y * 32;
    int tid = threadIdx.x;
    int i = tid >> 3, j4 = (tid & 7) * 4;
    #pragma unroll
    for (int rep = 0; rep < 64; rep += 32) {
        f32x4 w = *(const f32x4*)(v + (size_t)(t0 + i + rep) * HD + hd0 + j4);
        #pragma unroll
        for (int u = 0; u < 4; ++u)
            Tl[(j4 + u) * 68 + (i + rep)] = f8_quant_byte(w[u] / scale);
    }
    __syncthreads();
    int d = tid >> 3, tc = tid & 7;
    unsigned lo = *(const unsigned*)(&Tl[d * 68 + tc * 8]);
    unsigned hi = *(const unsigned*)(&Tl[d * 68 + tc * 8 + 4]);
    unsigned long long out = ((unsigned long long)hi << 32) | lo;
    *(unsigned long long*)(vt + (size_t)(hd0 + d) * total + t0 + tc * 8) = out;
}

// ---------- kernel 4: LDS-free MFMA flash attention ----------
// 4 independent waves/block, 16 q-rows each. Swapped QK^T (S^T = K*Q^T) puts
// q = lane&15 lane-local: in-register softmax, P exchanged to A-frag via shfl.
// V read pre-transposed (V8T) as direct 8B global loads, HW fp8 cvt to bf16.
__global__ __launch_bounds__(256)
void attn2_kernel(const float* __restrict__ Q,
                  const unsigned char* __restrict__ K8,
                  const unsigned char* __restrict__ V8T,
                  const int* __restrict__ q_off,
                  const int* __restrict__ k_off,
                  const int* __restrict__ k_lens,
                  const unsigned* __restrict__ amax,
                  float* __restrict__ out, int total, int nB) {
    const int h = blockIdx.y;
    const int tid = threadIdx.x;
    const int wid = tid >> 6, lane = tid & 63;
    const int g = lane >> 4, c = lane & 15;
    const int qw0 = blockIdx.x * 64 + wid * 16;
    if (qw0 >= total) return;

    // sequence lookup (assumes 16 | sequence boundaries)
    int b = 0;
    while (b + 1 < nB && q_off[b + 1] <= qw0) ++b;
    const int q_start = q_off[b];
    const int q_len   = q_off[b + 1] - q_start;
    const int seq_ks  = k_off[b];
    const int klen    = k_lens[b];
    const int dkl     = klen - q_len;

    int kmax = (qw0 + 15 - q_start) + dkl + 1;
    if (kmax > klen) kmax = klen;
    if (kmax < 0) kmax = 0;
    const int ntiles = (kmax + KVBLK - 1) / KVBLK;

    const float sq = __uint_as_float(amax[0]) / 448.0f;
    const float sk = __uint_as_float(amax[1]) / 448.0f;
    const float sv = __uint_as_float(amax[2]) / 448.0f;
    const float sscale = sq * sk * 0.08838834764831845f * 1.4426950408889634f; // fold log2e

    // Q fragment (B operand): col = lane&15 = q row qw0+c; k = d = s*32 + g*8 + i
    int qrow = qw0 + c; if (qrow >= total) qrow = total - 1;
    const float* qp = Q + (size_t)qrow * HD + h * Dd;
    long qfrag[4];
    #pragma unroll
    for (int s = 0; s < 4; ++s) {
        const float* qq = qp + s * 32 + g * 8;
        f32x4 va = *(const f32x4*)(qq);
        f32x4 vb = *(const f32x4*)(qq + 4);
        unsigned char by[8];
        #pragma unroll
        for (int i = 0; i < 4; ++i) by[i] = f8_quant_byte(va[i] / sq);
        #pragma unroll
        for (int i = 0; i < 4; ++i) by[4 + i] = f8_quant_byte(vb[i] / sq);
        qfrag[s] = pack8(by);
    }

    const int qlim = (qw0 + c) - q_start + dkl;   // causal: key <= qlim for q = qw0+c

    f32x4 Oacc[8];
    #pragma unroll
    for (int s = 0; s < 8; ++s) Oacc[s] = (f32x4){0.f, 0.f, 0.f, 0.f};
    float m = -1e30f, l = 0.f;

    const unsigned char* Kb = K8 + (size_t)seq_ks * HD + h * Dd;
    const unsigned char* Vt = V8T + (size_t)(h * Dd + c) * total + seq_ks;

    for (int kt = 0; kt < ntiles; ++kt) {
        const int t0 = kt * KVBLK;

        // ---- QK^T swapped: S^T = mfma(K, Q); rows = keys, cols = q ----
        int krow0 = t0 + c;      if (krow0 > klen - 1) krow0 = klen - 1;
        int krow1 = t0 + 16 + c; if (krow1 > klen - 1) krow1 = klen - 1;
        const unsigned char* kp0 = Kb + (size_t)krow0 * HD;
        const unsigned char* kp1 = Kb + (size_t)krow1 * HD;
        f32x4 S0 = {0.f, 0.f, 0.f, 0.f}, S1 = {0.f, 0.f, 0.f, 0.f};
        #pragma unroll
        for (int s = 0; s < 4; ++s) {
            long k0 = *(const long*)(kp0 + s * 32 + g * 8);
            long k1 = *(const long*)(kp1 + s * 32 + g * 8);
            S0 = __builtin_amdgcn_mfma_f32_16x16x32_fp8_fp8(k0, qfrag[s], S0, 0, 0, 0);
            S1 = __builtin_amdgcn_mfma_f32_16x16x32_fp8_fp8(k1, qfrag[s], S1, 0, 0, 0);
        }

        // ---- in-register online softmax for q = c (lane holds keys 4g+r, 16+4g+r) ----
        float sc[8];
        #pragma unroll
        for (int r = 0; r < 4; ++r) {
            sc[r]     = (t0 + g * 4 + r      > qlim) ? -3e38f : S0[r] * sscale;
            sc[4 + r] = (t0 + 16 + g * 4 + r > qlim) ? -3e38f : S1[r] * sscale;
        }
        float tmax = sc[0];
        #pragma unroll
        for (int j = 1; j < 8; ++j) tmax = fmaxf(tmax, sc[j]);
        tmax = fmaxf(tmax, __shfl_xor(tmax, 16, 64));
        tmax = fmaxf(tmax, __shfl_xor(tmax, 32, 64));
        float mn = fmaxf(m, tmax);
        float corr = EXP2F(m - mn);
        m = mn;
        float p[8], psum = 0.f;
        #pragma unroll
        for (int j = 0; j < 8; ++j) { p[j] = EXP2F(sc[j] - mn); psum += p[j]; }
        psum += __shfl_xor(psum, 16, 64);
        psum += __shfl_xor(psum, 32, 64);
        l = l * corr + psum;

        // rescale Oacc (rows are q = g*4+r; fetch corr from lane g*4+r)
        float corr_q[4];
        #pragma unroll
        for (int r = 0; r < 4; ++r) corr_q[r] = __shfl(corr, g * 4 + r, 64);
        #pragma unroll
        for (int sub = 0; sub < 8; ++sub)
            #pragma unroll
            for (int r = 0; r < 4; ++r) Oacc[sub][r] *= corr_q[r];

        // ---- P -> bf16 A-fragment via register exchange ----
        // lane (g,c): has keys {4g..4g+3, 16+4g..19+4g} for q=c; needs keys 8g..8g+7.
        unsigned pA = pk_bf16(p[0], p[1]), pB = pk_bf16(p[2], p[3]);
        unsigned pC = pk_bf16(p[4], p[5]), pD = pk_bf16(p[6], p[7]);
        int src0 = ((g & 1) << 5) + c, src1 = src0 + 16;
        unsigned a0 = __shfl(pA, src0, 64), b0 = __shfl(pB, src0, 64);
        unsigned c0 = __shfl(pC, src0, 64), d0 = __shfl(pD, src0, 64);
        unsigned a1 = __shfl(pA, src1, 64), b1 = __shfl(pB, src1, 64);
        unsigned c1 = __shfl(pC, src1, 64), d1 = __shfl(pD, src1, 64);
        bool losel = (g < 2);
        unsigned fr[4] = { losel ? a0 : c0, losel ? b0 : d0,
                           losel ? a1 : c1, losel ? b1 : d1 };
        s16x8 pa;
        ((unsigned*)&pa)[0] = fr[0]; ((unsigned*)&pa)[1] = fr[1];
        ((unsigned*)&pa)[2] = fr[2]; ((unsigned*)&pa)[3] = fr[3];

        // ---- PV: B-frag = V^T[d = c+16*sub][kv = t0+8g .. +7] direct from V8T ----
        const unsigned char* vt = Vt + t0 + g * 8;
        #pragma unroll
        for (int sub = 0; sub < 8; ++sub) {
            unsigned long long vb8 = *(const unsigned long long*)(vt + (size_t)sub * 16 * total);
            unsigned wlo = (unsigned)vb8, whi = (unsigned)(vb8 >> 32);
            f32x2 f01 = f8x2_to_f32(wlo, false), f23 = f8x2_to_f32(wlo, true);
            f32x2 f45 = f8x2_to_f32(whi, false), f67 = f8x2_to_f32(whi, true);
            s16x8 vbf;
            ((unsigned*)&vbf)[0] = pk_bf16(f01.x, f01.y);
            ((unsigned*)&vbf)[1] = pk_bf16(f23.x, f23.y);
            ((unsigned*)&vbf)[2] = pk_bf16(f45.x, f45.y);
            ((unsigned*)&vbf)[3] = pk_bf16(f67.x, f67.y);
            Oacc[sub] = __builtin_amdgcn_mfma_f32_16x16x32_bf16(pa, vbf, Oacc[sub], 0, 0, 0);
        }
    }

    // ---- epilogue: O[q = qw0+g*4+r][d = c+16*sub]; l lives at lane g*4+r ----
    #pragma unroll
    for (int r = 0; r < 4; ++r) {
        float lq = __shfl(l, g * 4 + r, 64);
        int t = qw0 + g * 4 + r;
        if (t < total) {
            float inv = (lq > 0.f) ? (sv / lq) : 0.f;
            float* op = out + (size_t)t * HD + h * Dd + c;
            #pragma unroll
            for (int sub = 0; sub < 8; ++sub) op[sub * 16] = Oacc[sub][r] * inv;
        }
    }
}

extern "C" void kernel_launch(void* const* d_in, const int* in_sizes, int n_in,
                              void* d_out, int out_size, void* d_ws, size_t ws_size,
                              hipStream_t stream) {
    const float* q = (const float*)d_in[0];
    const float* k = (const float*)d_in[1];
    const float* v = (const float*)d_in[2];
    const int* q_off  = (const int*)d_in[3];
    const int* k_off  = (const int*)d_in[4];
    const int* k_lens = (const int*)d_in[5];

    int total = in_sizes[0] / HD;          // 4096
    int B = in_sizes[3] - 1;               // 4
    int n = in_sizes[0];
    int n4 = n / 4;

    unsigned* amax = (unsigned*)d_ws;                          // [0]=q [1]=k [2]=v
    unsigned char* K8  = (unsigned char*)d_ws + 64;
    unsigned char* V8T = K8 + (size_t)n;

    (void)hipMemsetAsync(d_ws, 0, 64, stream);

    absmax_all_kernel<<<dim3(1024, 3), 256, 0, stream>>>(q, k, v, n4, amax);
    quant_kernel<<<2048, 256, 0, stream>>>(k, K8, n4, amax + 1);
    quant_vt_kernel<<<dim3(total / 64, HD / 32), 256, 0, stream>>>(v, V8T, total, amax + 2);

    dim3 grid(total / 64, Hh);
    attn2_kernel<<<grid, 256, 0, stream>>>(q, K8, V8T, q_off, k_off, k_lens,
                                           amax, (float*)d_out, total, B);
}